// Round 17
// baseline (249.709 us; speedup 1.0000x reference)
//
#include <hip/hip_runtime.h>

#define NN 100000
#define NE 3200000
#define HD 20
#define EHD 64
#define EOUTD 10
#define TBINS 4096
#define TROWS 24                   // 10 val + 10 delta + 4 pad, bf16 -> 48B row

// ---- radix/counting sort geometry ----
#define EPB 8192
#define NBLKS1 391                 // ceil(NE/EPB)
#define NBINS1 256                 // pass-1 bins: src>>9 in [0,196)
#define N1 (NBINS1 * NBLKS1)       // 100096
#define NBUCK 196
#define WIN 4096
#define WPB 6                      // windows per bucket
#define NWIN (NBUCK * WPB)         // 1176
#define N2 (NBUCK * 512 * WPB)     // 602112

// ---------------- generic scan: per-1024-block ----------------
__global__ void scan1_kernel(int* __restrict__ data, int* __restrict__ bsum, int n) {
    __shared__ int s[1024];
    int t = threadIdx.x;
    int i = blockIdx.x * 1024 + t;
    int v = (i < n) ? data[i] : 0;
    s[t] = v;
    __syncthreads();
    for (int off = 1; off < 1024; off <<= 1) {
        int add = (t >= off) ? s[t - off] : 0;
        __syncthreads();
        s[t] += add;
        __syncthreads();
    }
    if (i < n) data[i] = s[t] - v;            // exclusive, block-local
    if (t == 1023) bsum[blockIdx.x] = s[t];
}

__global__ void scan2_kernel(int* __restrict__ bsum, int nb) {
    __shared__ int s[1024];
    int t = threadIdx.x;
    int v = (t < nb) ? bsum[t] : 0;
    s[t] = v;
    __syncthreads();
    for (int off = 1; off < 1024; off <<= 1) {
        int add = (t >= off) ? s[t - off] : 0;
        __syncthreads();
        s[t] += add;
        __syncthreads();
    }
    if (t < nb) bsum[t] = s[t] - v;           // exclusive
}

__global__ void scan3_kernel(int* __restrict__ data, const int* __restrict__ bsum, int n) {
    int i = blockIdx.x * blockDim.x + threadIdx.x;
    if (i < n) data[i] += bsum[i >> 10];
}

// ---------------- pass 1 histogram (bin = src>>9) ----------------
__global__ void hist1_kernel(const int* __restrict__ ei, int* __restrict__ counts1) {
    __shared__ int h[NBINS1];
    int t = threadIdx.x;
    h[t] = 0;
    __syncthreads();
    int base = blockIdx.x * EPB;
    for (int j = t; j < EPB; j += 256) {
        int e = base + j;
        if (e < NE) atomicAdd(&h[ei[e] >> 9], 1);
    }
    __syncthreads();
    counts1[t * NBLKS1 + blockIdx.x] = h[t];     // bin-major
}

// ---------------- pass 1 scatter (unstable, LDS cursors) ----------------
__global__ void scatter1_kernel(const int* __restrict__ ei,
                                const float* __restrict__ ea,
                                const int* __restrict__ counts1s,
                                unsigned short* __restrict__ key1,
                                int2* __restrict__ pk1) {
    __shared__ int cur[NBINS1];
    int t = threadIdx.x;
    cur[t] = counts1s[t * NBLKS1 + blockIdx.x];
    __syncthreads();
    int base = blockIdx.x * EPB;
    for (int j = t; j < EPB; j += 256) {
        int e = base + j;
        if (e >= NE) break;
        int src = ei[e];
        int pos = atomicAdd(&cur[src >> 9], 1);
        key1[pos] = (unsigned short)(src & 511);
        int2 pk;
        pk.x = ei[NE + e];
        pk.y = __float_as_int(ea[e]);
        pk1[pos] = pk;
    }
}

// ---------------- pass 2 histogram ----------------
__global__ void hist2_kernel(const unsigned short* __restrict__ key1,
                             const int* __restrict__ counts1s,
                             int* __restrict__ M2) {
    __shared__ int h[512];
    int t = threadIdx.x;
    h[t] = 0; h[t + 256] = 0;
    __syncthreads();
    int b = blockIdx.x / WPB, w = blockIdx.x % WPB;
    int bstart = counts1s[b * NBLKS1];
    int bend   = counts1s[(b + 1) * NBLKS1];
    int start = bstart + w * WIN;
    int end = (start + WIN < bend) ? (start + WIN) : bend;
    for (int i = start + t; i < end; i += 256) atomicAdd(&h[key1[i]], 1);
    __syncthreads();
    M2[((b * 512) + t) * WPB + w]       = h[t];
    M2[((b * 512) + t + 256) * WPB + w] = h[t + 256];
}

// ---------------- pass 2 scatter (final positions) ----------------
__global__ void scatter2_kernel(const unsigned short* __restrict__ key1,
                                const int2* __restrict__ pk1,
                                const int* __restrict__ counts1s,
                                const int* __restrict__ M2s,
                                int2* __restrict__ csr_pk) {
    __shared__ int cur[512];
    int t = threadIdx.x;
    int b = blockIdx.x / WPB, w = blockIdx.x % WPB;
    cur[t]       = M2s[((b * 512) + t) * WPB + w];
    cur[t + 256] = M2s[((b * 512) + t + 256) * WPB + w];
    __syncthreads();
    int bstart = counts1s[b * NBLKS1];
    int bend   = counts1s[(b + 1) * NBLKS1];
    int start = bstart + w * WIN;
    int end = (start + WIN < bend) ? (start + WIN) : bend;
    for (int i = start + t; i < end; i += 256) {
        int pos = atomicAdd(&cur[key1[i]], 1);
        csr_pk[pos] = pk1[i];
    }
}

// ---------------- offsets from scanned M2 ----------------
__global__ void offs_kernel(const int* __restrict__ M2s, int* __restrict__ offsets) {
    int n = blockIdx.x * blockDim.x + threadIdx.x;
    if (n > NN) return;
    if (n == NN) { offsets[NN] = NE; return; }
    int b = n >> 9, bin = n & 511;
    offsets[n] = M2s[((b * 512) + bin) * WPB + 0];
}

// ---------------- MLP table: bf16 {val, delta} lerp rows -----------------
__global__ void table_kernel(const float* __restrict__ W1,
                             const float* __restrict__ b1,
                             const float* __restrict__ W2,
                             const float* __restrict__ b2,
                             unsigned short* __restrict__ tab) {
    int i = blockIdx.x * blockDim.x + threadIdx.x;
    if (i >= TBINS) return;
    float m0[EOUTD], m1[EOUTD];
    float d0 = (float)i * (10.0f / (float)TBINS);
    float d1 = (float)(i + 1) * (10.0f / (float)TBINS);
    #pragma unroll
    for (int j = 0; j < EOUTD; ++j) { m0[j] = b2[j]; m1[j] = b2[j]; }
    for (int k = 0; k < EHD; ++k) {
        float h0 = fmaxf(fmaf(d0, W1[k], b1[k]), 0.0f);
        float h1 = fmaxf(fmaf(d1, W1[k], b1[k]), 0.0f);
        #pragma unroll
        for (int j = 0; j < EOUTD; ++j) {
            m0[j] = fmaf(h0, W2[k * EOUTD + j], m0[j]);
            m1[j] = fmaf(h1, W2[k * EOUTD + j], m1[j]);
        }
    }
    unsigned short* row = tab + (size_t)i * TROWS;
    #pragma unroll
    for (int j = 0; j < EOUTD; ++j) {
        unsigned int uv = __float_as_uint(m0[j]);
        unsigned int ud = __float_as_uint(m1[j] - m0[j]);
        uv = (uv + 0x7fffu + ((uv >> 16) & 1u)) >> 16;
        ud = (ud + 0x7fffu + ((ud >> 16) & 1u)) >> 16;
        row[j] = (unsigned short)uv;
        row[10 + j] = (unsigned short)ud;
    }
    row[20] = 0; row[21] = 0; row[22] = 0; row[23] = 0;
}

// ---------------- bf16-pack x[:,0,:] into split tables -------------------
__global__ void xsplit_kernel(const float* __restrict__ x,
                              unsigned short* __restrict__ xlo,
                              unsigned short* __restrict__ xhi) {
    int t = blockIdx.x * blockDim.x + threadIdx.x;
    if (t >= NN * 10) return;
    int node = t / 10;
    int pr = t - node * 10;
    int j = pr * 2;
    float f0 = x[(size_t)node * 2 * HD + j];
    float f1 = x[(size_t)node * 2 * HD + j + 1];
    unsigned int u0 = __float_as_uint(f0);
    unsigned int u1 = __float_as_uint(f1);
    u0 = (u0 + 0x7fffu + ((u0 >> 16) & 1u)) >> 16;   // RNE bf16
    u1 = (u1 + 0x7fffu + ((u1 >> 16) & 1u)) >> 16;
    ushort2 p;
    p.x = (unsigned short)u0;
    p.y = (unsigned short)u1;
    if (pr < 8) *(ushort2*)(xlo + (size_t)node * 16 + j) = p;
    else        *(ushort2*)(xhi + (size_t)node * 4 + (j - 16)) = p;
}

// ---------------- node-owner kernel ----------------
__launch_bounds__(256)
__global__ void node_kernel(const int* __restrict__ offsets,
                            const int2* __restrict__ csr_pk,
                            const float* __restrict__ x,
                            const unsigned short* __restrict__ xlo,
                            const unsigned short* __restrict__ xhi,
                            const unsigned short* __restrict__ tab,
                            const float* __restrict__ pa,
                            const float* __restrict__ pb,
                            const float* __restrict__ g1,
                            const float* __restrict__ g2,
                            const float* __restrict__ bias,
                            float* __restrict__ out) {
    int tid  = threadIdx.x;
    int grp  = tid >> 4;          // 16 nodes per 256-thread block
    int lane = tid & 15;
    int node = blockIdx.x * 16 + grp;
    if (node >= NN) return;

    int off0 = offsets[node];
    int deg  = offsets[node + 1] - off0;
    float a = pa[0], bb = pb[0];
    float oma = 1.0f - a;

    float xs[HD], axs[HD];
    {
        const float4* xp = (const float4*)(x + (size_t)node * 2 * HD);
        #pragma unroll
        for (int q = 0; q < 5; ++q) {
            float4 v = xp[q];
            xs[4 * q] = v.x; xs[4 * q + 1] = v.y;
            xs[4 * q + 2] = v.z; xs[4 * q + 3] = v.w;
            axs[4 * q] = a * v.x; axs[4 * q + 1] = a * v.y;
            axs[4 * q + 2] = a * v.z; axs[4 * q + 3] = a * v.w;
        }
    }

    float S0[HD], S1[HD], Sr[HD];
    #pragma unroll
    for (int k = 0; k < HD; ++k) { S0[k] = 0.0f; S1[k] = 0.0f; Sr[k] = 0.0f; }

    // one edge: d, x-row (int4+int4+int2), table row bf16 val+delta (int4+int4+int2), fr
    auto edge = [&](float d, float fr, int4 XA, int4 XB, int2 XH,
                    int4 T0, int4 T1, int2 T2) {
        auto blo = [](int w) { return __uint_as_float(((unsigned int)w) << 16); };
        auto bhi = [](int w) { return __uint_as_float(((unsigned int)w) & 0xffff0000u); };
        float m[EOUTD];
        m[0] = fmaf(fr, blo(T1.y), blo(T0.x));
        m[1] = fmaf(fr, bhi(T1.y), bhi(T0.x));
        m[2] = fmaf(fr, blo(T1.z), blo(T0.y));
        m[3] = fmaf(fr, bhi(T1.z), bhi(T0.y));
        m[4] = fmaf(fr, blo(T1.w), blo(T0.z));
        m[5] = fmaf(fr, bhi(T1.w), bhi(T0.z));
        m[6] = fmaf(fr, blo(T2.x), blo(T0.w));
        m[7] = fmaf(fr, bhi(T2.x), bhi(T0.w));
        m[8] = fmaf(fr, blo(T2.y), blo(T1.x));
        m[9] = fmaf(fr, bhi(T2.y), bhi(T1.x));
        int idx = (int)d; if (idx > 9) idx = 9;

        int w[10];
        w[0] = XA.x; w[1] = XA.y; w[2] = XA.z; w[3] = XA.w;
        w[4] = XB.x; w[5] = XB.y; w[6] = XB.z; w[7] = XB.w;
        w[8] = XH.x; w[9] = XH.y;
        #pragma unroll
        for (int p = 0; p < 10; ++p) {
            int wp = w[p];
            float xxlo = blo(wp);
            float xxhi = bhi(wp);
            #pragma unroll
            for (int h = 0; h < 2; ++h) {
                const int k = 2 * p + h;
                float xdk = h ? xxhi : xxlo;
                float t = fmaf(-oma, xdk, axs[k]);
                float rho = (t != 0.0f)
                    ? __builtin_amdgcn_exp2f(bb * __builtin_amdgcn_logf(fabsf(t)))
                    : 0.0f;
                Sr[k] += rho;
                float comb = (k < 10) ? ((k == idx) ? 1.0f : 0.0f)
                                      : fmaxf(m[k - 10], 0.0f);
                S0[k] += comb;
                S1[k] = fmaf(rho, comb, S1[k]);
            }
        }
    };

    // batched first 2 strides: all loads issued up front; csr stream nontemporal
    {
        bool v0 = lane < deg;
        bool v1 = lane + 16 < deg;
        int p0 = v0 ? (off0 + lane) : off0;
        int p1 = v1 ? (off0 + lane + 16) : off0;
        if (p0 > NE - 1) p0 = NE - 1;
        if (p1 > NE - 1) p1 = NE - 1;
        long long q0 = __builtin_nontemporal_load((const long long*)&csr_pk[p0]);
        long long q1 = __builtin_nontemporal_load((const long long*)&csr_pk[p1]);
        unsigned int dst0 = (unsigned int)(q0 & 0xffffffffll);
        unsigned int dst1 = (unsigned int)(q1 & 0xffffffffll);
        float d0 = __int_as_float((int)(q0 >> 32));
        float d1 = __int_as_float((int)(q1 >> 32));
        float u0 = d0 * ((float)TBINS / 10.0f);
        float u1 = d1 * ((float)TBINS / 10.0f);
        int ti0 = (int)u0; if (ti0 > TBINS - 1) ti0 = TBINS - 1;
        int ti1 = (int)u1; if (ti1 > TBINS - 1) ti1 = TBINS - 1;
        float fr0 = u0 - (float)ti0;
        float fr1 = u1 - (float)ti1;
        const int4* rl0 = (const int4*)(xlo + (size_t)dst0 * 16);
        const int4* rl1 = (const int4*)(xlo + (size_t)dst1 * 16);
        const int2* rh0 = (const int2*)(xhi + (size_t)dst0 * 4);
        const int2* rh1 = (const int2*)(xhi + (size_t)dst1 * 4);
        const int4* tp0 = (const int4*)(tab + (size_t)ti0 * TROWS);
        const int4* tp1 = (const int4*)(tab + (size_t)ti1 * TROWS);
        int4 XA0 = rl0[0], XB0 = rl0[1];
        int2 XH0 = rh0[0];
        int4 XA1 = rl1[0], XB1 = rl1[1];
        int2 XH1 = rh1[0];
        int4 T00 = tp0[0], T01 = tp0[1];
        int2 T02 = ((const int2*)tp0)[4];
        int4 T10 = tp1[0], T11 = tp1[1];
        int2 T12 = ((const int2*)tp1)[4];
        if (v0) edge(d0, fr0, XA0, XB0, XH0, T00, T01, T02);
        if (v1) edge(d1, fr1, XA1, XB1, XH1, T10, T11, T12);
    }
    // rare tail (deg > 32)
    for (int i = lane + 32; i < deg; i += 16) {
        long long q = __builtin_nontemporal_load((const long long*)&csr_pk[off0 + i]);
        unsigned int dst = (unsigned int)(q & 0xffffffffll);
        float d = __int_as_float((int)(q >> 32));
        float u = d * ((float)TBINS / 10.0f);
        int ti = (int)u; if (ti > TBINS - 1) ti = TBINS - 1;
        float fr = u - (float)ti;
        const int4* rl = (const int4*)(xlo + (size_t)dst * 16);
        const int2* rh = (const int2*)(xhi + (size_t)dst * 4);
        const int4* tp = (const int4*)(tab + (size_t)ti * TROWS);
        int4 XA = rl[0], XB = rl[1];
        int2 XH = rh[0];
        int4 T0 = tp[0], T1 = tp[1];
        int2 T2 = ((const int2*)tp)[4];
        edge(d, fr, XA, XB, XH, T0, T1, T2);
    }

    #pragma unroll
    for (int s = 8; s >= 1; s >>= 1) {
        #pragma unroll
        for (int k = 0; k < HD; ++k) {
            S0[k] += __shfl_xor(S0[k], s, 16);
            S1[k] += __shfl_xor(S1[k], s, 16);
            Sr[k] += __shfl_xor(Sr[k], s, 16);
        }
    }

    float sf[HD];
    #pragma unroll
    for (int k = 0; k < HD; ++k)
        sf[k] = (S0[k] != 0.0f) ? (S1[k] / S0[k]) : (0.01f * Sr[k]);

    float* op = out + (size_t)node * 2 * HD;
    {
        int r = lane;
        float acc = bias[r];
        const float4* g1p = (const float4*)(g1 + r * HD);
        const float4* g2p = (const float4*)(g2 + r * HD);
        #pragma unroll
        for (int q = 0; q < 5; ++q) {
            float4 w1 = g1p[q], w2 = g2p[q];
            acc = fmaf(xs[4 * q], w1.x, acc); acc = fmaf(sf[4 * q], w2.x, acc);
            acc = fmaf(xs[4 * q + 1], w1.y, acc); acc = fmaf(sf[4 * q + 1], w2.y, acc);
            acc = fmaf(xs[4 * q + 2], w1.z, acc); acc = fmaf(sf[4 * q + 2], w2.z, acc);
            acc = fmaf(xs[4 * q + 3], w1.w, acc); acc = fmaf(sf[4 * q + 3], w2.w, acc);
        }
        float myv = 0.0f;
        #pragma unroll
        for (int k = 0; k < HD; ++k) if (r == k) myv = sf[k];
        op[r] = fmaxf(acc, 0.0f);
        op[HD + r] = myv;
    }
    if (lane < HD - 16) {
        int r = lane + 16;
        float acc = bias[r];
        const float4* g1p = (const float4*)(g1 + r * HD);
        const float4* g2p = (const float4*)(g2 + r * HD);
        #pragma unroll
        for (int q = 0; q < 5; ++q) {
            float4 w1 = g1p[q], w2 = g2p[q];
            acc = fmaf(xs[4 * q], w1.x, acc); acc = fmaf(sf[4 * q], w2.x, acc);
            acc = fmaf(xs[4 * q + 1], w1.y, acc); acc = fmaf(sf[4 * q + 1], w2.y, acc);
            acc = fmaf(xs[4 * q + 2], w1.z, acc); acc = fmaf(sf[4 * q + 2], w2.z, acc);
            acc = fmaf(xs[4 * q + 3], w1.w, acc); acc = fmaf(sf[4 * q + 3], w2.w, acc);
        }
        float myv = 0.0f;
        #pragma unroll
        for (int k = 0; k < HD; ++k) if (r == k) myv = sf[k];
        op[r] = fmaxf(acc, 0.0f);
        op[HD + r] = myv;
    }
}

extern "C" void kernel_launch(void* const* d_in, const int* in_sizes, int n_in,
                              void* d_out, int out_size, void* d_ws, size_t ws_size,
                              hipStream_t stream) {
    const float* x    = (const float*)d_in[0];
    const int*   ei   = (const int*)d_in[1];
    const float* ea   = (const float*)d_in[2];
    const float* pa   = (const float*)d_in[3];
    const float* pb   = (const float*)d_in[4];
    const float* g1   = (const float*)d_in[5];
    const float* g2   = (const float*)d_in[6];
    const float* bias = (const float*)d_in[7];
    const float* W1   = (const float*)d_in[8];
    const float* b1   = (const float*)d_in[9];
    const float* W2   = (const float*)d_in[10];
    const float* b2   = (const float*)d_in[11];
    float* out = (float*)d_out;

    // workspace layout (all segments 128B-aligned)
    char* ws = (char*)d_ws;
    int*   counts1 = (int*)ws;     ws += ((size_t)N1 * 4 + 127) / 128 * 128;
    int*   bsum1   = (int*)ws;     ws += (1024 * 4 + 127) / 128 * 128;
    int*   M2      = (int*)ws;     ws += ((size_t)N2 * 4 + 127) / 128 * 128;
    int*   bsum2   = (int*)ws;     ws += (1024 * 4 + 127) / 128 * 128;
    int*   offsets = (int*)ws;     ws += ((size_t)(NN + 1) * 4 + 127) / 128 * 128;
    unsigned short* key1 = (unsigned short*)ws;  ws += ((size_t)NE * 2 + 127) / 128 * 128;
    int2*  pk1     = (int2*)ws;    ws += (size_t)NE * 8;
    int2*  csr_pk  = (int2*)ws;    ws += (size_t)NE * 8;
    unsigned short* tab = (unsigned short*)ws;   ws += ((size_t)TBINS * TROWS * 2 + 127) / 128 * 128;
    unsigned short* xlo = (unsigned short*)ws;   ws += ((size_t)NN * 16 * 2 + 127) / 128 * 128;
    unsigned short* xhi = (unsigned short*)ws;   ws += ((size_t)NN * 4 * 2 + 127) / 128 * 128;

    table_kernel<<<(TBINS + 255) / 256, 256, 0, stream>>>(W1, b1, W2, b2, tab);
    xsplit_kernel<<<(NN * 10 + 255) / 256, 256, 0, stream>>>(x, xlo, xhi);

    // pass 1: group by bucket (src>>9)
    hist1_kernel<<<NBLKS1, 256, 0, stream>>>(ei, counts1);
    scan1_kernel<<<(N1 + 1023) / 1024, 1024, 0, stream>>>(counts1, bsum1, N1);
    scan2_kernel<<<1, 1024, 0, stream>>>(bsum1, (N1 + 1023) / 1024);
    scan3_kernel<<<(N1 + 255) / 256, 256, 0, stream>>>(counts1, bsum1, N1);
    scatter1_kernel<<<NBLKS1, 256, 0, stream>>>(ei, ea, counts1, key1, pk1);

    // pass 2: within bucket, bin = src & 511 (== exact node)
    hist2_kernel<<<NWIN, 256, 0, stream>>>(key1, counts1, M2);
    scan1_kernel<<<(N2 + 1023) / 1024, 1024, 0, stream>>>(M2, bsum2, N2);
    scan2_kernel<<<1, 1024, 0, stream>>>(bsum2, (N2 + 1023) / 1024);
    scan3_kernel<<<(N2 + 255) / 256, 256, 0, stream>>>(M2, bsum2, N2);
    scatter2_kernel<<<NWIN, 256, 0, stream>>>(key1, pk1, counts1, M2, csr_pk);

    offs_kernel<<<(NN + 256) / 256, 256, 0, stream>>>(M2, offsets);

    node_kernel<<<(NN + 15) / 16, 256, 0, stream>>>(offsets, csr_pk, x, xlo, xhi, tab,
                                                    pa, pb, g1, g2, bias, out);
}

// Round 19
// 248.240 us; speedup vs baseline: 1.0059x; 1.0059x over previous
//
#include <hip/hip_runtime.h>

#define NN 100000
#define NE 3200000
#define HD 20
#define EHD 64
#define EOUTD 10
#define TBINS 4096

// ---- radix/counting sort geometry ----
#define EPB 8192
#define NBLKS1 391                 // ceil(NE/EPB)
#define NBINS1 256                 // pass-1 bins: src>>9 in [0,196)
#define N1 (NBINS1 * NBLKS1)       // 100096
#define NBUCK 196
#define WIN 4096
#define WPB 6                      // windows per bucket
#define NWIN (NBUCK * WPB)         // 1176
#define N2 (NBUCK * 512 * WPB)     // 602112

// ---------------- generic scan: per-1024-block ----------------
__global__ void scan1_kernel(int* __restrict__ data, int* __restrict__ bsum, int n) {
    __shared__ int s[1024];
    int t = threadIdx.x;
    int i = blockIdx.x * 1024 + t;
    int v = (i < n) ? data[i] : 0;
    s[t] = v;
    __syncthreads();
    for (int off = 1; off < 1024; off <<= 1) {
        int add = (t >= off) ? s[t - off] : 0;
        __syncthreads();
        s[t] += add;
        __syncthreads();
    }
    if (i < n) data[i] = s[t] - v;            // exclusive, block-local
    if (t == 1023) bsum[blockIdx.x] = s[t];
}

__global__ void scan2_kernel(int* __restrict__ bsum, int nb) {
    __shared__ int s[1024];
    int t = threadIdx.x;
    int v = (t < nb) ? bsum[t] : 0;
    s[t] = v;
    __syncthreads();
    for (int off = 1; off < 1024; off <<= 1) {
        int add = (t >= off) ? s[t - off] : 0;
        __syncthreads();
        s[t] += add;
        __syncthreads();
    }
    if (t < nb) bsum[t] = s[t] - v;           // exclusive
}

__global__ void scan3_kernel(int* __restrict__ data, const int* __restrict__ bsum, int n) {
    int i = blockIdx.x * blockDim.x + threadIdx.x;
    if (i < n) data[i] += bsum[i >> 10];
}

// ---------------- pass 1 histogram (bin = src>>9) ----------------
__global__ void hist1_kernel(const int* __restrict__ ei, int* __restrict__ counts1) {
    __shared__ int h[NBINS1];
    int t = threadIdx.x;
    h[t] = 0;
    __syncthreads();
    int base = blockIdx.x * EPB;
    for (int j = t; j < EPB; j += 256) {
        int e = base + j;
        if (e < NE) atomicAdd(&h[ei[e] >> 9], 1);
    }
    __syncthreads();
    counts1[t * NBLKS1 + blockIdx.x] = h[t];     // bin-major
}

// ---------------- pass 1 scatter (unstable, LDS cursors) ----------------
__global__ void scatter1_kernel(const int* __restrict__ ei,
                                const float* __restrict__ ea,
                                const int* __restrict__ counts1s,
                                unsigned short* __restrict__ key1,
                                int2* __restrict__ pk1) {
    __shared__ int cur[NBINS1];
    int t = threadIdx.x;
    cur[t] = counts1s[t * NBLKS1 + blockIdx.x];
    __syncthreads();
    int base = blockIdx.x * EPB;
    for (int j = t; j < EPB; j += 256) {
        int e = base + j;
        if (e >= NE) break;
        int src = ei[e];
        int pos = atomicAdd(&cur[src >> 9], 1);
        key1[pos] = (unsigned short)(src & 511);
        int2 pk;
        pk.x = ei[NE + e];
        pk.y = __float_as_int(ea[e]);
        pk1[pos] = pk;
    }
}

// ---------------- pass 2 histogram ----------------
__global__ void hist2_kernel(const unsigned short* __restrict__ key1,
                             const int* __restrict__ counts1s,
                             int* __restrict__ M2) {
    __shared__ int h[512];
    int t = threadIdx.x;
    h[t] = 0; h[t + 256] = 0;
    __syncthreads();
    int b = blockIdx.x / WPB, w = blockIdx.x % WPB;
    int bstart = counts1s[b * NBLKS1];
    int bend   = counts1s[(b + 1) * NBLKS1];
    int start = bstart + w * WIN;
    int end = (start + WIN < bend) ? (start + WIN) : bend;
    for (int i = start + t; i < end; i += 256) atomicAdd(&h[key1[i]], 1);
    __syncthreads();
    M2[((b * 512) + t) * WPB + w]       = h[t];
    M2[((b * 512) + t + 256) * WPB + w] = h[t + 256];
}

// ---------------- pass 2 scatter (final positions) ----------------
__global__ void scatter2_kernel(const unsigned short* __restrict__ key1,
                                const int2* __restrict__ pk1,
                                const int* __restrict__ counts1s,
                                const int* __restrict__ M2s,
                                int2* __restrict__ csr_pk) {
    __shared__ int cur[512];
    int t = threadIdx.x;
    int b = blockIdx.x / WPB, w = blockIdx.x % WPB;
    cur[t]       = M2s[((b * 512) + t) * WPB + w];
    cur[t + 256] = M2s[((b * 512) + t + 256) * WPB + w];
    __syncthreads();
    int bstart = counts1s[b * NBLKS1];
    int bend   = counts1s[(b + 1) * NBLKS1];
    int start = bstart + w * WIN;
    int end = (start + WIN < bend) ? (start + WIN) : bend;
    for (int i = start + t; i < end; i += 256) {
        int pos = atomicAdd(&cur[key1[i]], 1);
        csr_pk[pos] = pk1[i];
    }
}

// ---------------- offsets from scanned M2 ----------------
__global__ void offs_kernel(const int* __restrict__ M2s, int* __restrict__ offsets) {
    int n = blockIdx.x * blockDim.x + threadIdx.x;
    if (n > NN) return;
    if (n == NN) { offsets[NN] = NE; return; }
    int b = n >> 9, bin = n & 511;
    offsets[n] = M2s[((b * 512) + bin) * WPB + 0];
}

// ---------------- MLP table: bf16 {val,delta} pairs, 64B rows ------------
// tab[ti*32 + 2*j] = val_j (bf16), tab[ti*32 + 2*j + 1] = delta_j (bf16)
__global__ void table_kernel(const float* __restrict__ W1,
                             const float* __restrict__ b1,
                             const float* __restrict__ W2,
                             const float* __restrict__ b2,
                             unsigned short* __restrict__ tab) {
    int i = blockIdx.x * blockDim.x + threadIdx.x;
    if (i >= TBINS) return;
    float m0[EOUTD], m1[EOUTD];
    float d0 = (float)i * (10.0f / (float)TBINS);
    float d1 = (float)(i + 1) * (10.0f / (float)TBINS);
    #pragma unroll
    for (int j = 0; j < EOUTD; ++j) { m0[j] = b2[j]; m1[j] = b2[j]; }
    for (int k = 0; k < EHD; ++k) {
        float h0 = fmaxf(fmaf(d0, W1[k], b1[k]), 0.0f);
        float h1 = fmaxf(fmaf(d1, W1[k], b1[k]), 0.0f);
        #pragma unroll
        for (int j = 0; j < EOUTD; ++j) {
            m0[j] = fmaf(h0, W2[k * EOUTD + j], m0[j]);
            m1[j] = fmaf(h1, W2[k * EOUTD + j], m1[j]);
        }
    }
    unsigned short* row = tab + (size_t)i * 32;
    #pragma unroll
    for (int j = 0; j < EOUTD; ++j) {
        unsigned int uv = __float_as_uint(m0[j]);
        unsigned int ud = __float_as_uint(m1[j] - m0[j]);
        uv = (uv + 0x7fffu + ((uv >> 16) & 1u)) >> 16;
        ud = (ud + 0x7fffu + ((ud >> 16) & 1u)) >> 16;
        row[2 * j]     = (unsigned short)uv;
        row[2 * j + 1] = (unsigned short)ud;
    }
    #pragma unroll
    for (int j = 20; j < 32; ++j) row[j] = 0;
}

// ---------------- bf16-pack x[:,0,:] into 64B line-aligned rows ----------
__global__ void xpack_kernel(const float* __restrict__ x,
                             unsigned short* __restrict__ xbf) {
    int t = blockIdx.x * blockDim.x + threadIdx.x;
    if (t >= NN * 32) return;
    int node = t >> 5, k = t & 31;
    unsigned short v = 0;
    if (k < HD) {
        unsigned int u = __float_as_uint(x[(size_t)node * 2 * HD + k]);
        u = (u + 0x7fffu + ((u >> 16) & 1u)) >> 16;   // RNE bf16
        v = (unsigned short)u;
    }
    xbf[t] = v;
}

// ---------------- node-owner kernel: feature-parallel (20 lanes/node) -----
// lane k of a node owns feature k; per edge the 20-lane group does ONE
// coalesced 40B xbf read (1 line) + ONE coalesced 40B tab read (lanes 10-19).
__launch_bounds__(256)
__global__ void node_kernel(const int* __restrict__ offsets,
                            const int2* __restrict__ csr_pk,
                            const float* __restrict__ x,
                            const unsigned short* __restrict__ xbf,
                            const unsigned short* __restrict__ tab,
                            const float* __restrict__ pa,
                            const float* __restrict__ pb,
                            const float* __restrict__ g1,
                            const float* __restrict__ g2,
                            const float* __restrict__ bias,
                            float* __restrict__ out) {
    int tid  = threadIdx.x;
    int wave = tid >> 6;
    int lane = tid & 63;
    int sub  = lane / 20;                  // 0..2 active, 3 = idle lanes
    int fk   = lane - sub * 20;            // feature id 0..19
    int node = blockIdx.x * 12 + wave * 3 + sub;
    bool active = (sub < 3) && (node < NN);

    float a = pa[0], bb = pb[0];
    float oma = 1.0f - a;

    int off0 = 0, deg = 0;
    float xs_k = 0.0f, axs_k = 0.0f;
    if (active) {
        off0 = offsets[node];
        deg  = offsets[node + 1] - off0;
        xs_k = x[(size_t)node * 2 * HD + fk];     // coalesced 80B per group
        axs_k = a * xs_k;
    }

    float S0 = 0.0f, S1 = 0.0f, Sr = 0.0f;

    for (int base = 0; base < deg; base += 20) {
        int nchunk = deg - base; if (nchunk > 20) nchunk = 20;
        // coalesced preload of this chunk's (dst,d) pairs
        int dstv = 0, dbits = 0;
        if (fk < nchunk) {                        // active implied (deg>0)
            int2 pk = csr_pk[off0 + base + fk];
            dstv = pk.x; dbits = pk.y;
        }
        // software-pipelined broadcast
        int dstN = __shfl(dstv, sub * 20, 64);
        int dbN  = __shfl(dbits, sub * 20, 64);
        for (int jj = 0; jj < nchunk; ++jj) {
            int dst = dstN;
            int db  = dbN;
            if (jj + 1 < nchunk) {
                dstN = __shfl(dstv, sub * 20 + jj + 1, 64);
                dbN  = __shfl(dbits, sub * 20 + jj + 1, 64);
            }
            // coalesced gather: 20 lanes read 40B of one 64B line
            unsigned short uw = xbf[((size_t)(unsigned int)dst << 5) + fk];
            float d = __int_as_float(db);
            float xdk = __uint_as_float(((unsigned int)uw) << 16);
            float t = fmaf(-oma, xdk, axs_k);
            float rho = (t != 0.0f)
                ? __builtin_amdgcn_exp2f(bb * __builtin_amdgcn_logf(fabsf(t)))
                : 0.0f;
            Sr += rho;
            float comb;
            if (fk < 10) {
                int idx = (int)d; if (idx > 9) idx = 9;
                comb = (fk == idx) ? 1.0f : 0.0f;
            } else {
                float u = d * ((float)TBINS / 10.0f);
                int ti = (int)u; if (ti > TBINS - 1) ti = TBINS - 1;
                float fr = u - (float)ti;
                unsigned int vd = *(const unsigned int*)(tab + ((size_t)ti << 5) + (fk - 10) * 2);
                float val = __uint_as_float(vd << 16);
                float del = __uint_as_float(vd & 0xffff0000u);
                comb = fmaxf(fmaf(fr, del, val), 0.0f);
            }
            S0 += comb;
            S1 = fmaf(rho, comb, S1);
        }
    }

    float sf = (S0 != 0.0f) ? (S1 / S0) : (0.01f * Sr);

    if (active) {
        // epilogue: lane fk computes output row fk via shfl-gather of xs/sf
        float acc = bias[fk];
        const float4* g1p = (const float4*)(g1 + fk * HD);
        const float4* g2p = (const float4*)(g2 + fk * HD);
        #pragma unroll
        for (int q = 0; q < 5; ++q) {
            float4 w1 = g1p[q], w2 = g2p[q];
            int h0 = sub * 20 + 4 * q;
            float x0 = __shfl(xs_k, h0, 64),     s0 = __shfl(sf, h0, 64);
            float x1 = __shfl(xs_k, h0 + 1, 64), s1 = __shfl(sf, h0 + 1, 64);
            float x2 = __shfl(xs_k, h0 + 2, 64), s2 = __shfl(sf, h0 + 2, 64);
            float x3 = __shfl(xs_k, h0 + 3, 64), s3 = __shfl(sf, h0 + 3, 64);
            acc = fmaf(x0, w1.x, acc); acc = fmaf(s0, w2.x, acc);
            acc = fmaf(x1, w1.y, acc); acc = fmaf(s1, w2.y, acc);
            acc = fmaf(x2, w1.z, acc); acc = fmaf(s2, w2.z, acc);
            acc = fmaf(x3, w1.w, acc); acc = fmaf(s3, w2.w, acc);
        }
        float* op = out + (size_t)node * 2 * HD;
        op[fk]      = fmaxf(acc, 0.0f);
        op[HD + fk] = sf;
    }
}

extern "C" void kernel_launch(void* const* d_in, const int* in_sizes, int n_in,
                              void* d_out, int out_size, void* d_ws, size_t ws_size,
                              hipStream_t stream) {
    const float* x    = (const float*)d_in[0];
    const int*   ei   = (const int*)d_in[1];
    const float* ea   = (const float*)d_in[2];
    const float* pa   = (const float*)d_in[3];
    const float* pb   = (const float*)d_in[4];
    const float* g1   = (const float*)d_in[5];
    const float* g2   = (const float*)d_in[6];
    const float* bias = (const float*)d_in[7];
    const float* W1   = (const float*)d_in[8];
    const float* b1   = (const float*)d_in[9];
    const float* W2   = (const float*)d_in[10];
    const float* b2   = (const float*)d_in[11];
    float* out = (float*)d_out;

    // workspace layout (all segments 128B-aligned)
    char* ws = (char*)d_ws;
    int*   counts1 = (int*)ws;     ws += ((size_t)N1 * 4 + 127) / 128 * 128;
    int*   bsum1   = (int*)ws;     ws += (1024 * 4 + 127) / 128 * 128;
    int*   M2      = (int*)ws;     ws += ((size_t)N2 * 4 + 127) / 128 * 128;
    int*   bsum2   = (int*)ws;     ws += (1024 * 4 + 127) / 128 * 128;
    int*   offsets = (int*)ws;     ws += ((size_t)(NN + 1) * 4 + 127) / 128 * 128;
    unsigned short* key1 = (unsigned short*)ws;  ws += ((size_t)NE * 2 + 127) / 128 * 128;
    int2*  pk1     = (int2*)ws;    ws += (size_t)NE * 8;
    int2*  csr_pk  = (int2*)ws;    ws += (size_t)NE * 8;
    unsigned short* tab = (unsigned short*)ws;   ws += ((size_t)TBINS * 32 * 2 + 127) / 128 * 128;
    unsigned short* xbf = (unsigned short*)ws;   ws += ((size_t)NN * 32 * 2 + 127) / 128 * 128;

    table_kernel<<<(TBINS + 255) / 256, 256, 0, stream>>>(W1, b1, W2, b2, tab);
    xpack_kernel<<<(NN * 32 + 255) / 256, 256, 0, stream>>>(x, xbf);

    // pass 1: group by bucket (src>>9)
    hist1_kernel<<<NBLKS1, 256, 0, stream>>>(ei, counts1);
    scan1_kernel<<<(N1 + 1023) / 1024, 1024, 0, stream>>>(counts1, bsum1, N1);
    scan2_kernel<<<1, 1024, 0, stream>>>(bsum1, (N1 + 1023) / 1024);
    scan3_kernel<<<(N1 + 255) / 256, 256, 0, stream>>>(counts1, bsum1, N1);
    scatter1_kernel<<<NBLKS1, 256, 0, stream>>>(ei, ea, counts1, key1, pk1);

    // pass 2: within bucket, bin = src & 511 (== exact node)
    hist2_kernel<<<NWIN, 256, 0, stream>>>(key1, counts1, M2);
    scan1_kernel<<<(N2 + 1023) / 1024, 1024, 0, stream>>>(M2, bsum2, N2);
    scan2_kernel<<<1, 1024, 0, stream>>>(bsum2, (N2 + 1023) / 1024);
    scan3_kernel<<<(N2 + 255) / 256, 256, 0, stream>>>(M2, bsum2, N2);
    scatter2_kernel<<<NWIN, 256, 0, stream>>>(key1, pk1, counts1, M2, csr_pk);

    offs_kernel<<<(NN + 256) / 256, 256, 0, stream>>>(M2, offsets);

    node_kernel<<<(NN + 11) / 12, 256, 0, stream>>>(offsets, csr_pk, x, xbf, tab,
                                                    pa, pb, g1, g2, bias, out);
}